// Round 4
// baseline (8882.432 us; speedup 1.0000x reference)
//
#include <hip/hip_runtime.h>

// Persistent cooperative LSTM decoder. NLAYERS=4, NHID=1024, NOUT=512, BSZ=64, STEPS=128.
// 256 blocks x 512 threads, 1 block/CU (LDS 141KB). Block (lyr, jt) owns 16 hidden cols:
//  - U gate weights K 0..511 in LDS (swizzled); K 512.. in per-wave registers (8-way K split)
//  - proj L weights in LDS on blocks 0..31; c state in LDS; h state bf16 ping-pong in ws
// Wavefront schedule w = s + lyr over 131 waves, one two-level grid barrier per wave.
// amdgpu_waves_per_eu(2,2): LDS caps us at 1 block/CU = 2 waves/EU anyway; pin the
// register allocator to the 256-VGPR budget so the ~210-reg working set doesn't spill
// (round 3: allocator chose 128 VGPR -> 240MB of scratch traffic, MfmaUtil 2%).

#define H      1024
#define B      64
#define NL     4
#define BH     (B * H)
#define NOUTD  512
#define NSCAN  127
#define NWAVES 131
#define RSTR   76   // transposed reduce stride (floats): 16B-aligned, 2-way banks per phase

typedef __attribute__((ext_vector_type(8))) short short8;
typedef __attribute__((ext_vector_type(4))) float f32x4;

__device__ __forceinline__ unsigned short f2bf(float x) {
  union { float f; unsigned int u; } v; v.f = x;
  unsigned int r = v.u + 0x7FFFu + ((v.u >> 16) & 1u);
  return (unsigned short)(r >> 16);
}
__device__ __forceinline__ short8 pack8(float4 a, float4 b) {
  short8 r;
  r[0] = (short)f2bf(a.x); r[1] = (short)f2bf(a.y);
  r[2] = (short)f2bf(a.z); r[3] = (short)f2bf(a.w);
  r[4] = (short)f2bf(b.x); r[5] = (short)f2bf(b.y);
  r[6] = (short)f2bf(b.z); r[7] = (short)f2bf(b.w);
  return r;
}
__device__ __forceinline__ float sigmoidf_(float x) {
  return 1.0f / (1.0f + __expf(-x));
}
__device__ __forceinline__ float tanhf_(float x) {
  float ax = fabsf(x);
  float t = __expf(-2.0f * ax);
  float r = 1.0f - 2.0f * t / (1.0f + t);
  return copysignf(r, x);
}

// Two-level grid barrier: 8 groups of 32 blocks, then 8 leaders at the root.
__device__ __forceinline__ void gridbar(unsigned* bar, unsigned n) {
  __threadfence();
  __syncthreads();
  if (threadIdx.x == 0) {
    const int g = blockIdx.x >> 5;
    unsigned* gcnt = bar + g * 32;
    unsigned* ggen = bar + 256 + g * 32;
    unsigned* rcnt = bar + 512;
    unsigned* rgen = bar + 544;
    unsigned a = __hip_atomic_fetch_add(gcnt, 1u, __ATOMIC_ACQ_REL, __HIP_MEMORY_SCOPE_AGENT);
    if (a == 31) {
      unsigned ra = __hip_atomic_fetch_add(rcnt, 1u, __ATOMIC_ACQ_REL, __HIP_MEMORY_SCOPE_AGENT);
      if (ra == 7) {
        __hip_atomic_store(rcnt, 0u, __ATOMIC_RELAXED, __HIP_MEMORY_SCOPE_AGENT);
        __hip_atomic_store(rgen, n, __ATOMIC_RELEASE, __HIP_MEMORY_SCOPE_AGENT);
      } else {
        while (__hip_atomic_load(rgen, __ATOMIC_RELAXED, __HIP_MEMORY_SCOPE_AGENT) < n)
          __builtin_amdgcn_s_sleep(1);
      }
      __hip_atomic_store(gcnt, 0u, __ATOMIC_RELAXED, __HIP_MEMORY_SCOPE_AGENT);
      __hip_atomic_store(ggen, n, __ATOMIC_RELEASE, __HIP_MEMORY_SCOPE_AGENT);
    } else {
      while (__hip_atomic_load(ggen, __ATOMIC_RELAXED, __HIP_MEMORY_SCOPE_AGENT) < n)
        __builtin_amdgcn_s_sleep(1);
    }
    __threadfence();
  }
  __syncthreads();
}

__global__ __launch_bounds__(512)
__attribute__((amdgpu_waves_per_eu(2, 2)))
void lstm_persist(
    const float* __restrict__ hx, const float* __restrict__ cx,
    const float* __restrict__ Wm, const float* __restrict__ Um,
    const float* __restrict__ Lm, float* __restrict__ out,
    unsigned short* __restrict__ hb, unsigned* __restrict__ bar) {
  __shared__ __align__(16) unsigned short WuL[64 * 512];   // 64 KB swizzled U (K 0..511)
  __shared__ __align__(16) unsigned short Lw[16 * 1024];   // 32 KB swizzled L (proj blocks)
  __shared__ __align__(16) float red[2][64 * RSTR];        // 38.9 KB transposed reduce
  __shared__ float cS[B * 16];                             // 4 KB cell state

  const int tid = threadIdx.x;
  const int q = tid >> 6;            // wave 0..7
  const int lane = tid & 63;
  const int l15 = lane & 15;
  const int lhi = lane >> 4;
  const int bid = blockIdx.x;
  const int lyr = bid >> 6;          // 0..3
  const int jt = bid & 63;           // 16-col group
  const bool isProj = (bid < 32);

  // ---------------- init: h (both ping-pong buffers) + c ----------------
  for (int e = tid; e < B * 16; e += 512) {
    const int b = e >> 4, jj = e & 15;
    const size_t gi = (size_t)lyr * BH + (size_t)b * H + jt * 16 + jj;
    const unsigned short hv = f2bf(hx[gi]);
    hb[gi] = hv;
    hb[(size_t)NL * BH + gi] = hv;
    cS[b * 16 + jj] = cx[gi];
  }

  // ---------------- weights: LDS U part (K 0..511), swizzled ----------------
  {
    const int lr = tid >> 3;                 // local gate row 0..63
    const int kb0 = (tid & 7) * 64;          // K base
    const int gr = (lr >> 4) * 1024 + jt * 16 + (lr & 15);
    const float* src = Um + ((size_t)lyr * 4096 + gr) * 1024 + kb0;
#pragma unroll
    for (int jc = 0; jc < 8; ++jc) {
      float4 f0 = *(const float4*)(src + jc * 8);
      float4 f1 = *(const float4*)(src + jc * 8 + 4);
      int byteoff = ((lr * 512 + kb0 + jc * 8) * 2) ^ ((lr & 7) << 4);
      *(short8*)((char*)WuL + byteoff) = pack8(f0, f1);
    }
  }

  // ---------------- proj L weights -> LDS (blocks 0..31), swizzled ----------------
  if (isProj) {
    const int r = tid >> 5;                  // out-row within 16
    const int ko = (tid & 31) * 32;          // K base
    const float* src = Lm + ((size_t)bid * 16 + r) * 1024 + ko;
#pragma unroll
    for (int jc = 0; jc < 4; ++jc) {
      float4 f0 = *(const float4*)(src + jc * 8);
      float4 f1 = *(const float4*)(src + jc * 8 + 4);
      int byteoff = ((r * 1024 + ko + jc * 8) * 2) ^ ((r & 7) << 4);
      *(short8*)((char*)Lw + byteoff) = pack8(f0, f1);
    }
  }

  // ---------------- register weights (K >= 512) ----------------
  short8 wreg[6][4];
  if (lyr == 0) {
#pragma unroll
    for (int c = 0; c < 2; ++c) {
      const int kk = 512 + 64 * q + 32 * c + 8 * lhi;
#pragma unroll
      for (int n = 0; n < 4; ++n) {
        const int gr = n * 1024 + jt * 16 + l15;
        const float* src = Um + (size_t)gr * 1024 + kk;
        wreg[c][n] = pack8(*(const float4*)src, *(const float4*)(src + 4));
      }
    }
  } else {
#pragma unroll
    for (int c = 0; c < 6; ++c) {
      const int kk = 512 + 192 * q + 32 * c + 8 * lhi;
#pragma unroll
      for (int n = 0; n < 4; ++n) {
        const int gr = n * 1024 + jt * 16 + l15;
        const float* src = (kk < 1024)
            ? (Um + ((size_t)lyr * 4096 + gr) * 1024 + kk)
            : (Wm + ((size_t)(lyr - 1) * 4096 + gr) * 1024 + (kk - 1024));
        wreg[c][n] = pack8(*(const float4*)src, *(const float4*)(src + 4));
      }
    }
  }

  unsigned barn = 1;
  gridbar(bar, barn++);

  // ---------------- wavefront loop ----------------
  for (int w = 0; w < NWAVES; ++w) {
    const int rd = (w + 1) & 1, wr = w & 1;
    const unsigned short* hrd = hb + (size_t)rd * NL * BH;
    unsigned short* hwr = hb + (size_t)wr * NL * BH;
    const int s = w - lyr;

    if (s >= 0 && s < NSCAN) {
      const unsigned short* baseU = hrd + (size_t)lyr * BH;
      const unsigned short* baseW = hrd + (size_t)(lyr > 0 ? lyr - 1 : 0) * BH;
      f32x4 acc[4][4];
#pragma unroll
      for (int m = 0; m < 4; ++m)
#pragma unroll
        for (int n = 0; n < 4; ++n) acc[m][n] = (f32x4){0.f, 0.f, 0.f, 0.f};

      // LDS-weight chunks (K 64q .. 64q+63)
#pragma unroll
      for (int c = 0; c < 2; ++c) {
        const int kk = 64 * q + 32 * c;
        short8 a[4];
#pragma unroll
        for (int m = 0; m < 4; ++m)
          a[m] = *(const short8*)(baseU + (size_t)(m * 16 + l15) * H + kk + 8 * lhi);
#pragma unroll
        for (int n = 0; n < 4; ++n) {
          const int byteoff = (((n * 16 + l15) * 512 + kk + 8 * lhi) * 2) ^ ((l15 & 7) << 4);
          short8 bb = *(const short8*)((const char*)WuL + byteoff);
#pragma unroll
          for (int m = 0; m < 4; ++m)
            acc[m][n] = __builtin_amdgcn_mfma_f32_16x16x32_bf16(a[m], bb, acc[m][n], 0, 0, 0);
        }
      }
      // register-weight chunks
      if (lyr == 0) {
#pragma unroll
        for (int c = 0; c < 2; ++c) {
          const int kk = 512 + 64 * q + 32 * c;
          short8 a[4];
#pragma unroll
          for (int m = 0; m < 4; ++m)
            a[m] = *(const short8*)(baseU + (size_t)(m * 16 + l15) * H + kk + 8 * lhi);
#pragma unroll
          for (int n = 0; n < 4; ++n)
#pragma unroll
            for (int m = 0; m < 4; ++m)
              acc[m][n] = __builtin_amdgcn_mfma_f32_16x16x32_bf16(a[m], wreg[c][n], acc[m][n], 0, 0, 0);
        }
      } else {
#pragma unroll
        for (int c = 0; c < 6; ++c) {
          const int kk = 512 + 192 * q + 32 * c;
          const unsigned short* ap = (kk < 1024) ? (baseU + kk) : (baseW + (kk - 1024));
          short8 a[4];
#pragma unroll
          for (int m = 0; m < 4; ++m)
            a[m] = *(const short8*)(ap + (size_t)(m * 16 + l15) * H + 8 * lhi);
#pragma unroll
          for (int n = 0; n < 4; ++n)
#pragma unroll
            for (int m = 0; m < 4; ++m)
              acc[m][n] = __builtin_amdgcn_mfma_f32_16x16x32_bf16(a[m], wreg[c][n], acc[m][n], 0, 0, 0);
        }
      }

      // transposed vectorized reduce: 8 partials -> red[0] + red[1]
      __syncthreads();
      {
        const int rr = q >> 1;
        float* tile = red[q & 1];
        for (int r = 0; r < 4; ++r) {
          if (rr == r) {
#pragma unroll
            for (int m = 0; m < 4; ++m)
#pragma unroll
              for (int n = 0; n < 4; ++n) {
                float* p = &tile[(n * 16 + l15) * RSTR + m * 16 + lhi * 4];
                if (r == 0) *(f32x4*)p = acc[m][n];
                else { f32x4 v = *(f32x4*)p; v += acc[m][n]; *(f32x4*)p = v; }
              }
          }
          __syncthreads();
        }
      }

      // fused LSTM cell (2 adjacent hidden units per thread)
      {
        const int u = tid * 2;
        const int b = u >> 4, jj = u & 15;  // jj even
        unsigned short hyv[2];
#pragma unroll
        for (int e = 0; e < 2; ++e) {
          const int j2 = jj + e;
          const float ig = red[0][(0 * 16 + j2) * RSTR + b] + red[1][(0 * 16 + j2) * RSTR + b];
          const float fg = red[0][(1 * 16 + j2) * RSTR + b] + red[1][(1 * 16 + j2) * RSTR + b];
          const float gg = red[0][(2 * 16 + j2) * RSTR + b] + red[1][(2 * 16 + j2) * RSTR + b];
          const float og = red[0][(3 * 16 + j2) * RSTR + b] + red[1][(3 * 16 + j2) * RSTR + b];
          const float i_ = sigmoidf_(ig);
          const float f_ = sigmoidf_(fg);
          const float g_ = tanhf_(gg);
          const float o_ = sigmoidf_(og);
          const float cv = f_ * cS[b * 16 + j2] + i_ * g_;
          cS[b * 16 + j2] = cv;
          hyv[e] = f2bf(o_ * tanhf_(cv));
        }
        *(ushort2*)(hwr + (size_t)lyr * BH + (size_t)b * H + jt * 16 + jj) =
            make_ushort2(hyv[0], hyv[1]);
      }
    }

    // projection out[t] = hy3 @ L^T on blocks 0..31 (L in LDS)
    if (isProj && (w == 0 || w >= 4)) {
      __syncthreads();  // protect red from cell reads above
      const int tt = (w == 0) ? 0 : (w - 3);
      const unsigned short* hy3 = hrd + (size_t)3 * BH;
      f32x4 pacc[4];
#pragma unroll
      for (int m = 0; m < 4; ++m) pacc[m] = (f32x4){0.f, 0.f, 0.f, 0.f};
#pragma unroll
      for (int c = 0; c < 4; ++c) {
        const int kk = 128 * q + 32 * c;
        const int byteoff = ((l15 * 1024 + kk + 8 * lhi) * 2) ^ ((l15 & 7) << 4);
        short8 bb = *(const short8*)((const char*)Lw + byteoff);
#pragma unroll
        for (int m = 0; m < 4; ++m) {
          short8 a = *(const short8*)(hy3 + (size_t)(m * 16 + l15) * H + kk + 8 * lhi);
          pacc[m] = __builtin_amdgcn_mfma_f32_16x16x32_bf16(a, bb, pacc[m], 0, 0, 0);
        }
      }
      {
        const int rr = q >> 1;
        float* tile = red[q & 1];
        for (int r = 0; r < 4; ++r) {
          if (rr == r) {
#pragma unroll
            for (int m = 0; m < 4; ++m) {
              float* p = &tile[l15 * RSTR + m * 16 + lhi * 4];
              if (r == 0) *(f32x4*)p = pacc[m];
              else { f32x4 v = *(f32x4*)p; v += pacc[m]; *(f32x4*)p = v; }
            }
          }
          __syncthreads();
        }
      }
      {
        const int u = tid * 2;
        const int b = u >> 4, cc = u & 15;  // cc even
        float2 o;
        o.x = red[0][cc * RSTR + b] + red[1][cc * RSTR + b];
        o.y = red[0][(cc + 1) * RSTR + b] + red[1][(cc + 1) * RSTR + b];
        *(float2*)&out[(size_t)tt * B * NOUTD + (size_t)b * NOUTD + bid * 16 + cc] = o;
      }
    }

    gridbar(bar, barn++);
  }
}

extern "C" void kernel_launch(void* const* d_in, const int* in_sizes, int n_in,
                              void* d_out, int out_size, void* d_ws, size_t ws_size,
                              hipStream_t stream) {
  const float* hx = (const float*)d_in[0];
  const float* cx = (const float*)d_in[1];
  const float* Wm = (const float*)d_in[2];
  const float* Um = (const float*)d_in[3];
  const float* Lm = (const float*)d_in[4];
  float* out = (float*)d_out;

  char* ws = (char*)d_ws;
  unsigned short* hb = (unsigned short*)ws;          // 2 x NL*BH bf16 = 1 MB
  unsigned* bar = (unsigned*)(ws + (1 << 20));       // 4 KB barrier state

  hipMemsetAsync(bar, 0, 4096, stream);

  void* args[] = {(void*)&hx, (void*)&cx, (void*)&Wm, (void*)&Um,
                  (void*)&Lm, (void*)&out, (void*)&hb, (void*)&bar};
  hipLaunchCooperativeKernel((const void*)lstm_persist, dim3(256), dim3(512),
                             args, 0, stream);
}

// Round 5
// 2867.512 us; speedup vs baseline: 3.0976x; 3.0976x over previous
//
#include <hip/hip_runtime.h>

// Persistent cooperative LSTM decoder. NLAYERS=4, NHID=1024, NOUT=512, BSZ=64, STEPS=128.
// 256 blocks x 512 threads, 1 block/CU (LDS 141KB). Block (lyr, jt) owns 16 hidden cols.
// Round-5 change: FENCE-FREE cross-XCD coherence. All h ping-pong traffic uses
// agent-scope RELAXED atomics (global_* sc1 -> Infinity Cache, bypassing the
// non-coherent per-XCD L2). gridbar has NO __threadfence (round 2-4: each fence
// emitted buffer_wbl2/inv = full L2 flush per block per step => ~60us/step stall).
// Ordering: s_waitcnt vmcnt(0) before barrier arrival drains sc1 stores to L3.

#define H      1024
#define B      64
#define NL     4
#define BH     (B * H)
#define NOUTD  512
#define NSCAN  127
#define NWAVES 131
#define RSTR   76   // transposed reduce stride (floats)

typedef __attribute__((ext_vector_type(8))) short short8;
typedef __attribute__((ext_vector_type(4))) float f32x4;

__device__ __forceinline__ unsigned short f2bf(float x) {
  union { float f; unsigned int u; } v; v.f = x;
  unsigned int r = v.u + 0x7FFFu + ((v.u >> 16) & 1u);
  return (unsigned short)(r >> 16);
}
__device__ __forceinline__ short8 pack8(float4 a, float4 b) {
  short8 r;
  r[0] = (short)f2bf(a.x); r[1] = (short)f2bf(a.y);
  r[2] = (short)f2bf(a.z); r[3] = (short)f2bf(a.w);
  r[4] = (short)f2bf(b.x); r[5] = (short)f2bf(b.y);
  r[6] = (short)f2bf(b.z); r[7] = (short)f2bf(b.w);
  return r;
}
__device__ __forceinline__ float sigmoidf_(float x) {
  return 1.0f / (1.0f + __expf(-x));
}
__device__ __forceinline__ float tanhf_(float x) {
  float ax = fabsf(x);
  float t = __expf(-2.0f * ax);
  float r = 1.0f - 2.0f * t / (1.0f + t);
  return copysignf(r, x);
}

// device-scope (L3-coherent, L2-bypassing) h accessors
__device__ __forceinline__ short8 ld_h8(const unsigned short* p) {
  union { short8 s; unsigned long long q[2]; } u;
  u.q[0] = __hip_atomic_load((const unsigned long long*)p, __ATOMIC_RELAXED,
                             __HIP_MEMORY_SCOPE_AGENT);
  u.q[1] = __hip_atomic_load(((const unsigned long long*)p) + 1, __ATOMIC_RELAXED,
                             __HIP_MEMORY_SCOPE_AGENT);
  return u.s;
}
__device__ __forceinline__ void st_h4(unsigned short* p, unsigned v) {
  __hip_atomic_store((unsigned*)p, v, __ATOMIC_RELAXED, __HIP_MEMORY_SCOPE_AGENT);
}

// Two-level grid barrier, fence-free: RELAXED atomics only.
__device__ __forceinline__ void gridbar(unsigned* bar, unsigned n) {
  asm volatile("s_waitcnt vmcnt(0)" ::: "memory");  // drain this wave's sc1 stores
  __syncthreads();
  if (threadIdx.x == 0) {
    const int g = blockIdx.x >> 5;
    unsigned* gcnt = bar + g * 32;
    unsigned* ggen = bar + 256 + g * 32;
    unsigned* rcnt = bar + 512;
    unsigned* rgen = bar + 544;
    unsigned a = __hip_atomic_fetch_add(gcnt, 1u, __ATOMIC_RELAXED, __HIP_MEMORY_SCOPE_AGENT);
    if (a == 31) {
      unsigned ra = __hip_atomic_fetch_add(rcnt, 1u, __ATOMIC_RELAXED, __HIP_MEMORY_SCOPE_AGENT);
      if (ra == 7) {
        __hip_atomic_store(rcnt, 0u, __ATOMIC_RELAXED, __HIP_MEMORY_SCOPE_AGENT);
        __hip_atomic_store(rgen, n, __ATOMIC_RELAXED, __HIP_MEMORY_SCOPE_AGENT);
      } else {
        while (__hip_atomic_load(rgen, __ATOMIC_RELAXED, __HIP_MEMORY_SCOPE_AGENT) < n)
          __builtin_amdgcn_s_sleep(1);
      }
      __hip_atomic_store(gcnt, 0u, __ATOMIC_RELAXED, __HIP_MEMORY_SCOPE_AGENT);
      __hip_atomic_store(ggen, n, __ATOMIC_RELAXED, __HIP_MEMORY_SCOPE_AGENT);
    } else {
      while (__hip_atomic_load(ggen, __ATOMIC_RELAXED, __HIP_MEMORY_SCOPE_AGENT) < n)
        __builtin_amdgcn_s_sleep(1);
    }
    asm volatile("" ::: "memory");
  }
  __syncthreads();
}

__global__ __launch_bounds__(512)
__attribute__((amdgpu_waves_per_eu(2, 2)))
void lstm_persist(
    const float* __restrict__ hx, const float* __restrict__ cx,
    const float* __restrict__ Wm, const float* __restrict__ Um,
    const float* __restrict__ Lm, float* __restrict__ out,
    unsigned short* __restrict__ hb, unsigned* __restrict__ bar) {
  __shared__ __align__(16) unsigned short WuL[64 * 512];   // 64 KB swizzled U (K 0..511)
  __shared__ __align__(16) unsigned short Lw[16 * 1024];   // 32 KB swizzled L (proj blocks)
  __shared__ __align__(16) float red[2][64 * RSTR];        // 38.9 KB transposed reduce
  __shared__ float cS[B * 16];                             // 4 KB cell state

  const int tid = threadIdx.x;
  const int q = tid >> 6;            // wave 0..7
  const int lane = tid & 63;
  const int l15 = lane & 15;
  const int lhi = lane >> 4;
  const int bid = blockIdx.x;
  const int lyr = bid >> 6;          // 0..3
  const int jt = bid & 63;           // 16-col group
  const bool isProj = (bid < 32);

  // ---------------- init: h (both ping-pong buffers, sc1 stores) + c ----------------
  {
    const int u = tid * 2;                  // 512 threads x 2 cols = 1024 units
    const int b = u >> 4, jj = u & 15;      // jj even
    const size_t gi = (size_t)lyr * BH + (size_t)b * H + jt * 16 + jj;
    const unsigned hv = (unsigned)f2bf(hx[gi]) | ((unsigned)f2bf(hx[gi + 1]) << 16);
    st_h4(hb + gi, hv);
    st_h4(hb + (size_t)NL * BH + gi, hv);
    cS[b * 16 + jj] = cx[gi];
    cS[b * 16 + jj + 1] = cx[gi + 1];
  }

  // ---------------- weights: LDS U part (K 0..511), swizzled ----------------
  {
    const int lr = tid >> 3;                 // local gate row 0..63
    const int kb0 = (tid & 7) * 64;          // K base
    const int gr = (lr >> 4) * 1024 + jt * 16 + (lr & 15);
    const float* src = Um + ((size_t)lyr * 4096 + gr) * 1024 + kb0;
#pragma unroll
    for (int jc = 0; jc < 8; ++jc) {
      float4 f0 = *(const float4*)(src + jc * 8);
      float4 f1 = *(const float4*)(src + jc * 8 + 4);
      int byteoff = ((lr * 512 + kb0 + jc * 8) * 2) ^ ((lr & 7) << 4);
      *(short8*)((char*)WuL + byteoff) = pack8(f0, f1);
    }
  }

  // ---------------- proj L weights -> LDS (blocks 0..31), swizzled ----------------
  if (isProj) {
    const int r = tid >> 5;                  // out-row within 16
    const int ko = (tid & 31) * 32;          // K base
    const float* src = Lm + ((size_t)bid * 16 + r) * 1024 + ko;
#pragma unroll
    for (int jc = 0; jc < 4; ++jc) {
      float4 f0 = *(const float4*)(src + jc * 8);
      float4 f1 = *(const float4*)(src + jc * 8 + 4);
      int byteoff = ((r * 1024 + ko + jc * 8) * 2) ^ ((r & 7) << 4);
      *(short8*)((char*)Lw + byteoff) = pack8(f0, f1);
    }
  }

  // ---------------- register weights (K >= 512) ----------------
  short8 wreg[6][4];
  if (lyr == 0) {
#pragma unroll
    for (int c = 0; c < 2; ++c) {
      const int kk = 512 + 64 * q + 32 * c + 8 * lhi;
#pragma unroll
      for (int n = 0; n < 4; ++n) {
        const int gr = n * 1024 + jt * 16 + l15;
        const float* src = Um + (size_t)gr * 1024 + kk;
        wreg[c][n] = pack8(*(const float4*)src, *(const float4*)(src + 4));
      }
    }
  } else {
#pragma unroll
    for (int c = 0; c < 6; ++c) {
      const int kk = 512 + 192 * q + 32 * c + 8 * lhi;
#pragma unroll
      for (int n = 0; n < 4; ++n) {
        const int gr = n * 1024 + jt * 16 + l15;
        const float* src = (kk < 1024)
            ? (Um + ((size_t)lyr * 4096 + gr) * 1024 + kk)
            : (Wm + ((size_t)(lyr - 1) * 4096 + gr) * 1024 + (kk - 1024));
        wreg[c][n] = pack8(*(const float4*)src, *(const float4*)(src + 4));
      }
    }
  }

  unsigned barn = 1;
  gridbar(bar, barn++);

  // ---------------- wavefront loop ----------------
  for (int w = 0; w < NWAVES; ++w) {
    const int rd = (w + 1) & 1, wr = w & 1;
    const unsigned short* hrd = hb + (size_t)rd * NL * BH;
    unsigned short* hwr = hb + (size_t)wr * NL * BH;
    const int s = w - lyr;

    if (s >= 0 && s < NSCAN) {
      const unsigned short* baseU = hrd + (size_t)lyr * BH;
      const unsigned short* baseW = hrd + (size_t)(lyr > 0 ? lyr - 1 : 0) * BH;
      f32x4 acc[4][4];
#pragma unroll
      for (int m = 0; m < 4; ++m)
#pragma unroll
        for (int n = 0; n < 4; ++n) acc[m][n] = (f32x4){0.f, 0.f, 0.f, 0.f};

      // LDS-weight chunks (K 64q .. 64q+63)
#pragma unroll
      for (int c = 0; c < 2; ++c) {
        const int kk = 64 * q + 32 * c;
        short8 a[4];
#pragma unroll
        for (int m = 0; m < 4; ++m)
          a[m] = ld_h8(baseU + (size_t)(m * 16 + l15) * H + kk + 8 * lhi);
#pragma unroll
        for (int n = 0; n < 4; ++n) {
          const int byteoff = (((n * 16 + l15) * 512 + kk + 8 * lhi) * 2) ^ ((l15 & 7) << 4);
          short8 bb = *(const short8*)((const char*)WuL + byteoff);
#pragma unroll
          for (int m = 0; m < 4; ++m)
            acc[m][n] = __builtin_amdgcn_mfma_f32_16x16x32_bf16(a[m], bb, acc[m][n], 0, 0, 0);
        }
      }
      // register-weight chunks
      if (lyr == 0) {
#pragma unroll
        for (int c = 0; c < 2; ++c) {
          const int kk = 512 + 64 * q + 32 * c;
          short8 a[4];
#pragma unroll
          for (int m = 0; m < 4; ++m)
            a[m] = ld_h8(baseU + (size_t)(m * 16 + l15) * H + kk + 8 * lhi);
#pragma unroll
          for (int n = 0; n < 4; ++n)
#pragma unroll
            for (int m = 0; m < 4; ++m)
              acc[m][n] = __builtin_amdgcn_mfma_f32_16x16x32_bf16(a[m], wreg[c][n], acc[m][n], 0, 0, 0);
        }
      } else {
#pragma unroll
        for (int c = 0; c < 6; ++c) {
          const int kk = 512 + 192 * q + 32 * c;
          const unsigned short* ap = (kk < 1024) ? (baseU + kk) : (baseW + (kk - 1024));
          short8 a[4];
#pragma unroll
          for (int m = 0; m < 4; ++m)
            a[m] = ld_h8(ap + (size_t)(m * 16 + l15) * H + 8 * lhi);
#pragma unroll
          for (int n = 0; n < 4; ++n)
#pragma unroll
            for (int m = 0; m < 4; ++m)
              acc[m][n] = __builtin_amdgcn_mfma_f32_16x16x32_bf16(a[m], wreg[c][n], acc[m][n], 0, 0, 0);
        }
      }

      // transposed vectorized reduce: 8 partials -> red[0] + red[1]
      __syncthreads();
      {
        const int rr = q >> 1;
        float* tile = red[q & 1];
        for (int r = 0; r < 4; ++r) {
          if (rr == r) {
#pragma unroll
            for (int m = 0; m < 4; ++m)
#pragma unroll
              for (int n = 0; n < 4; ++n) {
                float* p = &tile[(n * 16 + l15) * RSTR + m * 16 + lhi * 4];
                if (r == 0) *(f32x4*)p = acc[m][n];
                else { f32x4 v = *(f32x4*)p; v += acc[m][n]; *(f32x4*)p = v; }
              }
          }
          __syncthreads();
        }
      }

      // fused LSTM cell (2 adjacent hidden units per thread)
      {
        const int u = tid * 2;
        const int b = u >> 4, jj = u & 15;  // jj even
        unsigned short hyv[2];
#pragma unroll
        for (int e = 0; e < 2; ++e) {
          const int j2 = jj + e;
          const float ig = red[0][(0 * 16 + j2) * RSTR + b] + red[1][(0 * 16 + j2) * RSTR + b];
          const float fg = red[0][(1 * 16 + j2) * RSTR + b] + red[1][(1 * 16 + j2) * RSTR + b];
          const float gg = red[0][(2 * 16 + j2) * RSTR + b] + red[1][(2 * 16 + j2) * RSTR + b];
          const float og = red[0][(3 * 16 + j2) * RSTR + b] + red[1][(3 * 16 + j2) * RSTR + b];
          const float i_ = sigmoidf_(ig);
          const float f_ = sigmoidf_(fg);
          const float g_ = tanhf_(gg);
          const float o_ = sigmoidf_(og);
          const float cv = f_ * cS[b * 16 + j2] + i_ * g_;
          cS[b * 16 + j2] = cv;
          hyv[e] = f2bf(o_ * tanhf_(cv));
        }
        st_h4(hwr + (size_t)lyr * BH + (size_t)b * H + jt * 16 + jj,
              (unsigned)hyv[0] | ((unsigned)hyv[1] << 16));
      }
    }

    // projection out[t] = hy3 @ L^T on blocks 0..31 (L in LDS)
    if (isProj && (w == 0 || w >= 4)) {
      __syncthreads();  // protect red from cell reads above
      const int tt = (w == 0) ? 0 : (w - 3);
      const unsigned short* hy3 = hrd + (size_t)3 * BH;
      f32x4 pacc[4];
#pragma unroll
      for (int m = 0; m < 4; ++m) pacc[m] = (f32x4){0.f, 0.f, 0.f, 0.f};
#pragma unroll
      for (int c = 0; c < 4; ++c) {
        const int kk = 128 * q + 32 * c;
        const int byteoff = ((l15 * 1024 + kk + 8 * lhi) * 2) ^ ((l15 & 7) << 4);
        short8 bb = *(const short8*)((const char*)Lw + byteoff);
#pragma unroll
        for (int m = 0; m < 4; ++m) {
          short8 a = ld_h8(hy3 + (size_t)(m * 16 + l15) * H + kk + 8 * lhi);
          pacc[m] = __builtin_amdgcn_mfma_f32_16x16x32_bf16(a, bb, pacc[m], 0, 0, 0);
        }
      }
      {
        const int rr = q >> 1;
        float* tile = red[q & 1];
        for (int r = 0; r < 4; ++r) {
          if (rr == r) {
#pragma unroll
            for (int m = 0; m < 4; ++m) {
              float* p = &tile[l15 * RSTR + m * 16 + lhi * 4];
              if (r == 0) *(f32x4*)p = pacc[m];
              else { f32x4 v = *(f32x4*)p; v += pacc[m]; *(f32x4*)p = v; }
            }
          }
          __syncthreads();
        }
      }
      {
        const int u = tid * 2;
        const int b = u >> 4, cc = u & 15;  // cc even
        float2 o;
        o.x = red[0][cc * RSTR + b] + red[1][cc * RSTR + b];
        o.y = red[0][(cc + 1) * RSTR + b] + red[1][(cc + 1) * RSTR + b];
        *(float2*)&out[(size_t)tt * B * NOUTD + (size_t)b * NOUTD + bid * 16 + cc] = o;
      }
    }

    gridbar(bar, barn++);
  }
}

extern "C" void kernel_launch(void* const* d_in, const int* in_sizes, int n_in,
                              void* d_out, int out_size, void* d_ws, size_t ws_size,
                              hipStream_t stream) {
  const float* hx = (const float*)d_in[0];
  const float* cx = (const float*)d_in[1];
  const float* Wm = (const float*)d_in[2];
  const float* Um = (const float*)d_in[3];
  const float* Lm = (const float*)d_in[4];
  float* out = (float*)d_out;

  char* ws = (char*)d_ws;
  unsigned short* hb = (unsigned short*)ws;          // 2 x NL*BH bf16 = 1 MB
  unsigned* bar = (unsigned*)(ws + (1 << 20));       // 4 KB barrier state

  hipMemsetAsync(bar, 0, 4096, stream);

  void* args[] = {(void*)&hx, (void*)&cx, (void*)&Wm, (void*)&Um,
                  (void*)&Lm, (void*)&out, (void*)&hb, (void*)&bar};
  hipLaunchCooperativeKernel((const void*)lstm_persist, dim3(256), dim3(512),
                             args, 0, stream);
}

// Round 6
// 1674.824 us; speedup vs baseline: 5.3035x; 1.7121x over previous
//
#include <hip/hip_runtime.h>

// Persistent cooperative LSTM decoder. NLAYERS=4, NHID=1024, NOUT=512, BSZ=64, STEPS=128.
// 256 blocks x 512 threads, 1 block/CU. Block (lyr, jt) owns 16 hidden cols of layer lyr.
// - U/W gate weights: K 0..767 in LDS (96KB, swizzled); K 768.. in registers (80 VGPR, 8-way K split)
// - c state in LDS; h state bf16 ping-pong in ws (sc0/sc1 = IC-coherent, fence-free)
// - A-operand loads: 16B global_load_dwordx4 sc0 sc1 inline asm, depth-2 counted-vmcnt pipeline
// - projection REMOVED from the loop: lyr-3 blocks append hy3 to a history buffer; a separate
//   batched GEMM kernel (proj_kernel) computes all 128 outputs afterwards.

#define H      1024
#define B      64
#define NL     4
#define BH     (B * H)
#define NOUTD  512
#define NSCAN  127
#define NWAVES 131
#define RSTR   76   // transposed reduce stride (floats)
#define KL     768  // K columns resident in LDS per gate-row

typedef __attribute__((ext_vector_type(8))) short short8;
typedef __attribute__((ext_vector_type(4))) float f32x4;

__device__ __forceinline__ unsigned short f2bf(float x) {
  union { float f; unsigned int u; } v; v.f = x;
  unsigned int r = v.u + 0x7FFFu + ((v.u >> 16) & 1u);
  return (unsigned short)(r >> 16);
}
__device__ __forceinline__ short8 pack8(float4 a, float4 b) {
  short8 r;
  r[0] = (short)f2bf(a.x); r[1] = (short)f2bf(a.y);
  r[2] = (short)f2bf(a.z); r[3] = (short)f2bf(a.w);
  r[4] = (short)f2bf(b.x); r[5] = (short)f2bf(b.y);
  r[6] = (short)f2bf(b.z); r[7] = (short)f2bf(b.w);
  return r;
}
__device__ __forceinline__ float sigmoidf_(float x) {
  return 1.0f / (1.0f + __expf(-x));
}
__device__ __forceinline__ float tanhf_(float x) {
  float ax = fabsf(x);
  float t = __expf(-2.0f * ax);
  float r = 1.0f - 2.0f * t / (1.0f + t);
  return copysignf(r, x);
}

// 16B L2-bypassing (IC-coherent) load, async: consume only after a vmcnt wait.
__device__ __forceinline__ void ldg16(short8* d, const unsigned short* p) {
  asm volatile("global_load_dwordx4 %0, %1, off sc0 sc1" : "=v"(*d) : "v"(p));
}
#define VMWAIT4 do { asm volatile("s_waitcnt vmcnt(4)" ::: "memory"); \
                     __builtin_amdgcn_sched_barrier(0); } while (0)
#define VMWAIT0 do { asm volatile("s_waitcnt vmcnt(0)" ::: "memory"); \
                     __builtin_amdgcn_sched_barrier(0); } while (0)

__device__ __forceinline__ void st_h4(unsigned short* p, unsigned v) {
  __hip_atomic_store((unsigned*)p, v, __ATOMIC_RELAXED, __HIP_MEMORY_SCOPE_AGENT);
}

// Two-level grid barrier, fence-free (round-5 verified).
__device__ __forceinline__ void gridbar(unsigned* bar, unsigned n) {
  asm volatile("s_waitcnt vmcnt(0)" ::: "memory");
  __syncthreads();
  if (threadIdx.x == 0) {
    const int g = blockIdx.x >> 5;
    unsigned* gcnt = bar + g * 32;
    unsigned* ggen = bar + 256 + g * 32;
    unsigned* rcnt = bar + 512;
    unsigned* rgen = bar + 544;
    unsigned a = __hip_atomic_fetch_add(gcnt, 1u, __ATOMIC_RELAXED, __HIP_MEMORY_SCOPE_AGENT);
    if (a == 31) {
      unsigned ra = __hip_atomic_fetch_add(rcnt, 1u, __ATOMIC_RELAXED, __HIP_MEMORY_SCOPE_AGENT);
      if (ra == 7) {
        __hip_atomic_store(rcnt, 0u, __ATOMIC_RELAXED, __HIP_MEMORY_SCOPE_AGENT);
        __hip_atomic_store(rgen, n, __ATOMIC_RELAXED, __HIP_MEMORY_SCOPE_AGENT);
      } else {
        while (__hip_atomic_load(rgen, __ATOMIC_RELAXED, __HIP_MEMORY_SCOPE_AGENT) < n)
          __builtin_amdgcn_s_sleep(1);
      }
      __hip_atomic_store(gcnt, 0u, __ATOMIC_RELAXED, __HIP_MEMORY_SCOPE_AGENT);
      __hip_atomic_store(ggen, n, __ATOMIC_RELAXED, __HIP_MEMORY_SCOPE_AGENT);
    } else {
      while (__hip_atomic_load(ggen, __ATOMIC_RELAXED, __HIP_MEMORY_SCOPE_AGENT) < n)
        __builtin_amdgcn_s_sleep(1);
    }
    asm volatile("" ::: "memory");
  }
  __syncthreads();
}

__global__ __launch_bounds__(512, 2)
__attribute__((amdgpu_waves_per_eu(2, 2)))
void lstm_persist(
    const float* __restrict__ hx, const float* __restrict__ cx,
    const float* __restrict__ Wm, const float* __restrict__ Um,
    float* __restrict__ out,
    unsigned short* __restrict__ hb, unsigned short* __restrict__ hist,
    unsigned* __restrict__ bar) {
  __shared__ __align__(16) unsigned short WuL[64 * KL];    // 96 KB swizzled gate weights (K 0..767)
  __shared__ __align__(16) float red[2][64 * RSTR];        // 38.9 KB transposed reduce
  __shared__ float cS[B * 16];                             // 4 KB cell state

  const int tid = threadIdx.x;
  const int q = tid >> 6;            // wave 0..7
  const int lane = tid & 63;
  const int l15 = lane & 15;
  const int lhi = lane >> 4;
  const int bid = blockIdx.x;
  const int lyr = bid >> 6;          // 0..3
  const int jt = bid & 63;           // 16-col group

  // ---------------- init: h (both ping-pong buffers) + c + hist[0] ----------------
  {
    const int u = tid * 2;
    const int b = u >> 4, jj = u & 15;      // jj even
    const size_t gi = (size_t)lyr * BH + (size_t)b * H + jt * 16 + jj;
    const unsigned hv = (unsigned)f2bf(hx[gi]) | ((unsigned)f2bf(hx[gi + 1]) << 16);
    st_h4(hb + gi, hv);
    st_h4(hb + (size_t)NL * BH + gi, hv);
    if (lyr == 3) *(unsigned*)(hist + (size_t)b * H + jt * 16 + jj) = hv;
    cS[b * 16 + jj] = cx[gi];
    cS[b * 16 + jj + 1] = cx[gi + 1];
  }

  // ---------------- weights: LDS part (K 0..767), swizzled ----------------
  {
    const int lr = tid >> 3;                 // local gate row 0..63
    const int kb0 = (tid & 7) * 96;          // K base (96 cols per thread)
    const int gr = (lr >> 4) * 1024 + jt * 16 + (lr & 15);
    const float* src = Um + ((size_t)lyr * 4096 + gr) * 1024 + kb0;
#pragma unroll
    for (int jc = 0; jc < 12; ++jc) {
      float4 f0 = *(const float4*)(src + jc * 8);
      float4 f1 = *(const float4*)(src + jc * 8 + 4);
      int byteoff = ((lr * KL + kb0 + jc * 8) * 2) ^ ((lr & 7) << 4);
      *(short8*)((char*)WuL + byteoff) = pack8(f0, f1);
    }
  }

  // ---------------- register weights (K >= 768): 5 chunks lyr>0, 1 chunk lyr0 ----------------
  short8 wreg[5][4];
  if (lyr == 0) {
    const int kk = KL + 32 * q + 8 * lhi;    // 768..1023
#pragma unroll
    for (int n = 0; n < 4; ++n) {
      const int gr = n * 1024 + jt * 16 + l15;
      const float* src = Um + (size_t)gr * 1024 + kk;
      wreg[0][n] = pack8(*(const float4*)src, *(const float4*)(src + 4));
    }
  } else {
#pragma unroll
    for (int c = 0; c < 5; ++c) {
      const int kk = KL + 160 * q + 32 * c + 8 * lhi;   // 768..2047
#pragma unroll
      for (int n = 0; n < 4; ++n) {
        const int gr = n * 1024 + jt * 16 + l15;
        const float* src = (kk < 1024)
            ? (Um + ((size_t)lyr * 4096 + gr) * 1024 + kk)
            : (Wm + ((size_t)(lyr - 1) * 4096 + gr) * 1024 + (kk - 1024));
        wreg[c][n] = pack8(*(const float4*)src, *(const float4*)(src + 4));
      }
    }
  }

  unsigned barn = 1;
  gridbar(bar, barn++);

  // ---------------- wavefront loop ----------------
  for (int w = 0; w < NWAVES; ++w) {
    const int rd = (w + 1) & 1, wr = w & 1;
    const unsigned short* hrd = hb + (size_t)rd * NL * BH;
    unsigned short* hwr = hb + (size_t)wr * NL * BH;
    const int s = w - lyr;

    if (s >= 0 && s < NSCAN) {
      const unsigned short* baseU = hrd + (size_t)lyr * BH;
      const unsigned short* baseW = hrd + (size_t)(lyr > 0 ? lyr - 1 : 0) * BH;
      const unsigned short* aU = baseU + (size_t)l15 * H + 8 * lhi;
      const unsigned short* aW = baseW + (size_t)l15 * H + 8 * lhi;

      f32x4 acc[4][4];
#pragma unroll
      for (int m = 0; m < 4; ++m)
#pragma unroll
        for (int n = 0; n < 4; ++n) acc[m][n] = (f32x4){0.f, 0.f, 0.f, 0.f};

      short8 A[2][4];

#define KCOL0(c)  (96 * q + 32 * (c))                         // LDS-weight chunks (c<3)
#define KCOLR(c)  (KL + 160 * q + 32 * ((c) - 3))             // reg-weight chunks lyr>0
#define ISSUE(buf, k) { \
    const unsigned short* _p = ((k) < 1024) ? (aU + (k)) : (aW + ((k) - 1024)); \
    ldg16(&A[buf][0], _p); \
    ldg16(&A[buf][1], _p + 16 * H); \
    ldg16(&A[buf][2], _p + 32 * H); \
    ldg16(&A[buf][3], _p + 48 * H); }

      if (lyr > 0) {
        ISSUE(0, KCOL0(0));
        ISSUE(1, KCOL0(1));
#pragma unroll
        for (int c = 0; c < 8; ++c) {
          if (c < 7) VMWAIT4; else VMWAIT0;
          const int kk = (c < 3) ? KCOL0(c) : KCOLR(c);
          if (c < 3) {
#pragma unroll
            for (int n = 0; n < 4; ++n) {
              const int byteoff = (((n * 16 + l15) * KL + kk + 8 * lhi) * 2) ^ ((l15 & 7) << 4);
              short8 bb = *(const short8*)((const char*)WuL + byteoff);
#pragma unroll
              for (int m = 0; m < 4; ++m)
                acc[m][n] = __builtin_amdgcn_mfma_f32_16x16x32_bf16(A[c & 1][m], bb, acc[m][n], 0, 0, 0);
            }
          } else {
#pragma unroll
            for (int n = 0; n < 4; ++n)
#pragma unroll
              for (int m = 0; m < 4; ++m)
                acc[m][n] = __builtin_amdgcn_mfma_f32_16x16x32_bf16(A[c & 1][m], wreg[c - 3][n], acc[m][n], 0, 0, 0);
          }
          if (c + 2 < 8) {
            const int k2 = (c + 2 < 3) ? KCOL0(c + 2) : KCOLR(c + 2);
            ISSUE(c & 1, k2);
          }
        }
      } else {
        ISSUE(0, KCOL0(0));
        ISSUE(1, KCOL0(1));
#pragma unroll
        for (int c = 0; c < 4; ++c) {
          if (c < 3) VMWAIT4; else VMWAIT0;
          const int kk = (c < 3) ? KCOL0(c) : (KL + 32 * q);
          if (c < 3) {
#pragma unroll
            for (int n = 0; n < 4; ++n) {
              const int byteoff = (((n * 16 + l15) * KL + kk + 8 * lhi) * 2) ^ ((l15 & 7) << 4);
              short8 bb = *(const short8*)((const char*)WuL + byteoff);
#pragma unroll
              for (int m = 0; m < 4; ++m)
                acc[m][n] = __builtin_amdgcn_mfma_f32_16x16x32_bf16(A[c & 1][m], bb, acc[m][n], 0, 0, 0);
            }
          } else {
#pragma unroll
            for (int n = 0; n < 4; ++n)
#pragma unroll
              for (int m = 0; m < 4; ++m)
                acc[m][n] = __builtin_amdgcn_mfma_f32_16x16x32_bf16(A[c & 1][m], wreg[0][n], acc[m][n], 0, 0, 0);
          }
          if (c + 2 < 4) ISSUE(c & 1, KCOL0(c + 2));
        }
      }
#undef ISSUE
#undef KCOL0
#undef KCOLR

      // transposed vectorized reduce: 8 partials -> red[0] + red[1]
      __syncthreads();
      {
        const int rr = q >> 1;
        float* tile = red[q & 1];
        for (int r = 0; r < 4; ++r) {
          if (rr == r) {
#pragma unroll
            for (int m = 0; m < 4; ++m)
#pragma unroll
              for (int n = 0; n < 4; ++n) {
                float* p = &tile[(n * 16 + l15) * RSTR + m * 16 + lhi * 4];
                if (r == 0) *(f32x4*)p = acc[m][n];
                else { f32x4 v = *(f32x4*)p; v += acc[m][n]; *(f32x4*)p = v; }
              }
          }
          __syncthreads();
        }
      }

      // fused LSTM cell (2 adjacent hidden units per thread)
      {
        const int u = tid * 2;
        const int b = u >> 4, jj = u & 15;  // jj even
        unsigned short hyv[2];
#pragma unroll
        for (int e = 0; e < 2; ++e) {
          const int j2 = jj + e;
          const float ig = red[0][(0 * 16 + j2) * RSTR + b] + red[1][(0 * 16 + j2) * RSTR + b];
          const float fg = red[0][(1 * 16 + j2) * RSTR + b] + red[1][(1 * 16 + j2) * RSTR + b];
          const float gg = red[0][(2 * 16 + j2) * RSTR + b] + red[1][(2 * 16 + j2) * RSTR + b];
          const float og = red[0][(3 * 16 + j2) * RSTR + b] + red[1][(3 * 16 + j2) * RSTR + b];
          const float i_ = sigmoidf_(ig);
          const float f_ = sigmoidf_(fg);
          const float g_ = tanhf_(gg);
          const float o_ = sigmoidf_(og);
          const float cv = f_ * cS[b * 16 + j2] + i_ * g_;
          cS[b * 16 + j2] = cv;
          hyv[e] = f2bf(o_ * tanhf_(cv));
        }
        const unsigned packed = (unsigned)hyv[0] | ((unsigned)hyv[1] << 16);
        st_h4(hwr + (size_t)lyr * BH + (size_t)b * H + jt * 16 + jj, packed);
        if (lyr == 3)   // history for the batched output projection (t = s+1)
          *(unsigned*)(hist + (size_t)(s + 1) * BH + (size_t)b * H + jt * 16 + jj) = packed;
      }
    }

    gridbar(bar, barn++);
  }
}

// ---------------- batched output projection: out[t] = hist[t] @ L^T ----------------
// M = 128*64 = 8192 rows, N = 512, K = 1024. grid = 128 Mtiles x 8 Ntiles, 256 thr.
__global__ __launch_bounds__(256) void proj_kernel(
    const unsigned short* __restrict__ hist, const float* __restrict__ Lm,
    float* __restrict__ out) {
  __shared__ __align__(16) unsigned short As[64 * 136];
  const int tid = threadIdx.x;
  const int q = tid >> 6;
  const int lane = tid & 63;
  const int l15 = lane & 15;
  const int lhi = lane >> 4;
  const int mt = blockIdx.x >> 3;
  const int nt = blockIdx.x & 7;

  f32x4 acc[4];
#pragma unroll
  for (int m = 0; m < 4; ++m) acc[m] = (f32x4){0.f, 0.f, 0.f, 0.f};

  for (int kb = 0; kb < 8; ++kb) {
    __syncthreads();
#pragma unroll
    for (int i = 0; i < 4; ++i) {
      int g = tid + 256 * i;
      int row = g >> 4, cu = g & 15;
      *(short8*)(&As[row * 136 + cu * 8]) =
          *(const short8*)(&hist[((size_t)mt * 64 + row) * H + kb * 128 + cu * 8]);
    }
    __syncthreads();
#pragma unroll
    for (int kk = 0; kk < 4; ++kk) {
      const int ko = kk * 32 + 8 * lhi;
      const float* src = Lm + ((size_t)nt * 64 + q * 16 + l15) * H + kb * 128 + ko;
      short8 bb = pack8(*(const float4*)src, *(const float4*)(src + 4));
#pragma unroll
      for (int m = 0; m < 4; ++m) {
        short8 a = *(const short8*)(&As[(m * 16 + l15) * 136 + ko]);
        acc[m] = __builtin_amdgcn_mfma_f32_16x16x32_bf16(a, bb, acc[m], 0, 0, 0);
      }
    }
  }
  const int col = nt * 64 + q * 16 + l15;
#pragma unroll
  for (int m = 0; m < 4; ++m)
#pragma unroll
    for (int j = 0; j < 4; ++j) {
      const int row = mt * 64 + m * 16 + lhi * 4 + j;
      out[(size_t)row * NOUTD + col] = acc[m][j];
    }
}

extern "C" void kernel_launch(void* const* d_in, const int* in_sizes, int n_in,
                              void* d_out, int out_size, void* d_ws, size_t ws_size,
                              hipStream_t stream) {
  const float* hx = (const float*)d_in[0];
  const float* cx = (const float*)d_in[1];
  const float* Wm = (const float*)d_in[2];
  const float* Um = (const float*)d_in[3];
  const float* Lm = (const float*)d_in[4];
  float* out = (float*)d_out;

  char* ws = (char*)d_ws;
  unsigned short* hb = (unsigned short*)ws;                  // 1 MB ping-pong h
  unsigned* bar = (unsigned*)(ws + (1 << 20));               // 4 KB barrier state
  unsigned short* hist = (unsigned short*)(ws + (1 << 20) + 65536);  // 16 MB hy3 history

  hipMemsetAsync(bar, 0, 4096, stream);

  void* args[] = {(void*)&hx, (void*)&cx, (void*)&Wm, (void*)&Um,
                  (void*)&out, (void*)&hb, (void*)&hist, (void*)&bar};
  hipLaunchCooperativeKernel((const void*)lstm_persist, dim3(256), dim3(512),
                             args, 0, stream);
  proj_kernel<<<dim3(1024), dim3(256), 0, stream>>>(hist, Lm, out);
}